// Round 1
// baseline (150.196 us; speedup 1.0000x reference)
//
#include <hip/hip_runtime.h>
#include <hip/hip_bf16.h>
#include <math.h>

#define T_DIM 32
#define B_DIM 128
#define D_DIM 512
#define M_DIM 1024
#define ROWS (T_DIM * B_DIM)

constexpr float DT = 3.0f / 16.0f;   // t_max / (KNOTS-1)

// ---------------- Kernel 1: column inverse norms of A ----------------
__global__ __launch_bounds__(256) void colnorm_kernel(const float* __restrict__ A,
                                                      float* __restrict__ invn) {
    int m = blockIdx.x * 256 + threadIdx.x;          // 1024 columns, 4 blocks
    float ss = 0.0f;
    for (int d = 0; d < D_DIM; ++d) {
        float v = A[(size_t)d * M_DIM + m];          // coalesced across lanes
        ss = fmaf(v, v, ss);
    }
    float n = sqrtf(ss);
    invn[m] = 1.0f / fmaxf(n, 1e-12f);
}

// ---------------- Kernel 2: fp32 tiled GEMM  proj = z * (A * invn) ----------------
// C tile 64x64, 256 threads, 4x4 microtile, BK=16.
constexpr int BM = 64, BN = 64, BK = 16;

__global__ __launch_bounds__(256) void gemm_kernel(const float* __restrict__ z,
                                                   const float* __restrict__ A,
                                                   const float* __restrict__ invn,
                                                   float* __restrict__ proj,
                                                   int rowOff) {
    __shared__ float As[BK][BM];   // [k][row]
    __shared__ float Bs[BK][BN];   // [k][col]

    const int tid = threadIdx.x;
    const int lRowBlk = blockIdx.x * BM;             // chunk-local row base (proj)
    const int gRowBlk = rowOff + lRowBlk;            // global row base (z)
    const int colBlk  = blockIdx.y * BN;

    const int tr = tid >> 4;      // 0..15 thread row
    const int tc = tid & 15;      // 0..15 thread col

    // load mappings
    const int lr  = tid >> 2;     // 0..63  A-tile row
    const int lc4 = tid & 3;      // 0..3   A-tile float4 within 16 k's
    const int bkr = tid >> 4;     // 0..15  B-tile k row
    const int bc4 = tid & 15;     // 0..15  B-tile float4 col

    float acc[4][4] = {{0.f}};

    for (int k0 = 0; k0 < D_DIM; k0 += BK) {
        const float4 av = *reinterpret_cast<const float4*>(
            &z[(size_t)(gRowBlk + lr) * D_DIM + k0 + lc4 * 4]);
        const float4 bv = *reinterpret_cast<const float4*>(
            &A[(size_t)(k0 + bkr) * M_DIM + colBlk + bc4 * 4]);

        __syncthreads();   // previous iteration's reads complete
        As[lc4 * 4 + 0][lr] = av.x;
        As[lc4 * 4 + 1][lr] = av.y;
        As[lc4 * 4 + 2][lr] = av.z;
        As[lc4 * 4 + 3][lr] = av.w;
        *reinterpret_cast<float4*>(&Bs[bkr][bc4 * 4]) = bv;
        __syncthreads();

#pragma unroll
        for (int kk = 0; kk < BK; ++kk) {
            const float4 a4 = *reinterpret_cast<const float4*>(&As[kk][tr * 4]);
            const float4 b4 = *reinterpret_cast<const float4*>(&Bs[kk][tc * 4]);
            const float ar[4] = {a4.x, a4.y, a4.z, a4.w};
            const float br[4] = {b4.x, b4.y, b4.z, b4.w};
#pragma unroll
            for (int i = 0; i < 4; ++i)
#pragma unroll
                for (int j = 0; j < 4; ++j)
                    acc[i][j] = fmaf(ar[i], br[j], acc[i][j]);
        }
    }

    // epilogue: scale columns by invn, store
    const float4 sc4 = *reinterpret_cast<const float4*>(&invn[colBlk + tc * 4]);
    const float scr[4] = {sc4.x, sc4.y, sc4.z, sc4.w};
#pragma unroll
    for (int i = 0; i < 4; ++i) {
        float4 o;
        o.x = acc[i][0] * scr[0];
        o.y = acc[i][1] * scr[1];
        o.z = acc[i][2] * scr[2];
        o.w = acc[i][3] * scr[3];
        *reinterpret_cast<float4*>(
            &proj[(size_t)(lRowBlk + tr * 4 + i) * M_DIM + colBlk + tc * 4]) = o;
    }
}

// ---------------- Kernel 3: per-(t,m) CF statistic, block partials ----------------
// thread = one (t, m); loop over b; sincos once + 16-step angle-addition recurrence.
__global__ __launch_bounds__(256) void stat_kernel(const float* __restrict__ proj,
                                                   float* __restrict__ partials,
                                                   int partialOff) {
    const int tid = threadIdx.x;
    const int gid = blockIdx.x * 256 + tid;     // chunk-local (t,m) id
    const int lt  = gid >> 10;                  // chunk-local t
    const int m   = gid & 1023;

    float accC[16] = {0.f};   // k = 1..16 (k=0 term is exactly 0)
    float accS[16] = {0.f};

    const float* p = proj + (size_t)lt * B_DIM * M_DIM + m;
    for (int b = 0; b < B_DIM; ++b) {
        const float x = p[(size_t)b * M_DIM];   // coalesced across lanes
        float s1, c1;
        sincosf(x * DT, &s1, &c1);
        float c = c1, s = s1;
        accC[0] += c;
        accS[0] += s;
#pragma unroll
        for (int k = 1; k < 16; ++k) {
            const float cn = fmaf(c, c1, -s * s1);
            const float sn = fmaf(s, c1,  c * s1);
            c = cn; s = sn;
            accC[k] += c;
            accS[k] += s;
        }
    }

    float stat = 0.0f;
#pragma unroll
    for (int k = 1; k <= 16; ++k) {
        const float tk = DT * (float)k;
        const float g  = expf(-0.5f * tk * tk);
        const float w  = ((k == 16) ? DT : 2.0f * DT) * g;
        const float cm = accC[k - 1] * (1.0f / (float)B_DIM) - g;
        const float sm = accS[k - 1] * (1.0f / (float)B_DIM);
        stat = fmaf(w, fmaf(cm, cm, sm * sm), stat);
    }
    stat *= (float)B_DIM;

    // deterministic block reduction
    __shared__ float red[256];
    red[tid] = stat;
    __syncthreads();
    for (int s = 128; s > 0; s >>= 1) {
        if (tid < s) red[tid] += red[tid + s];
        __syncthreads();
    }
    if (tid == 0) partials[partialOff + blockIdx.x] = red[0];
}

// ---------------- Kernel 4: final reduce of 128 partials ----------------
__global__ __launch_bounds__(128) void finalize_kernel(const float* __restrict__ partials,
                                                       float* __restrict__ out) {
    __shared__ float red[128];
    const int tid = threadIdx.x;
    red[tid] = partials[tid];
    __syncthreads();
    for (int s = 64; s > 0; s >>= 1) {
        if (tid < s) red[tid] += red[tid + s];
        __syncthreads();
    }
    if (tid == 0) out[0] = red[0] * (1.0f / (float)(T_DIM * M_DIM));
}

extern "C" void kernel_launch(void* const* d_in, const int* in_sizes, int n_in,
                              void* d_out, int out_size, void* d_ws, size_t ws_size,
                              hipStream_t stream) {
    const float* z = (const float*)d_in[0];   // (32,128,512)
    const float* A = (const float*)d_in[1];   // (512,1024)
    float* out = (float*)d_out;

    float* invn     = (float*)d_ws;                       // 1024 floats
    float* partials = invn + M_DIM;                       // 128 floats
    float* proj     = partials + 128;                     // chunkT*128*1024 floats

    // how many t-slices of proj fit in the remaining workspace?
    const size_t headFloats = M_DIM + 128;
    const size_t availFloats = (ws_size / 4 > headFloats) ? (ws_size / 4 - headFloats) : 0;
    const size_t perT = (size_t)B_DIM * M_DIM;            // 131072 floats per t
    int chunkT = (int)(availFloats / perT);
    if (chunkT > T_DIM) chunkT = T_DIM;
    if (chunkT < 1) return;                               // workspace too small (unexpected)

    colnorm_kernel<<<M_DIM / 256, 256, 0, stream>>>(A, invn);

    int partialOff = 0;
    for (int t0 = 0; t0 < T_DIM; t0 += chunkT) {
        const int ct = (t0 + chunkT <= T_DIM) ? chunkT : (T_DIM - t0);
        const int chunkRows = ct * B_DIM;

        dim3 g(chunkRows / BM, M_DIM / BN);
        gemm_kernel<<<g, 256, 0, stream>>>(z, A, invn, proj, t0 * B_DIM);

        const int statBlocks = ct * M_DIM / 256;          // 4 per t
        stat_kernel<<<statBlocks, 256, 0, stream>>>(proj, partials, partialOff);
        partialOff += statBlocks;
    }

    finalize_kernel<<<1, 128, 0, stream>>>(partials, out);
}

// Round 2
// 53.947 us; speedup vs baseline: 2.7841x; 2.7841x over previous
//
#include <hip/hip_runtime.h>
#include <hip/hip_bf16.h>
#include <math.h>

#define T_DIM 32
#define B_DIM 128
#define D_DIM 512
#define M_DIM 1024

constexpr float DT = 0.1875f;            // 3.0 / 16

typedef __attribute__((ext_vector_type(8))) short bf16x8;   // 8 bf16 = 4 VGPR
typedef __attribute__((ext_vector_type(4))) float f32x4;    // MFMA acc

__device__ __forceinline__ ushort f2bf(float f) {           // RNE fp32->bf16
    unsigned u = __float_as_uint(f);
    u += 0x7FFFu + ((u >> 16) & 1u);
    return (ushort)(u >> 16);
}

// ---------- K1: column inverse norms of A (1024 cols) ----------
__global__ __launch_bounds__(256) void colnorm_kernel(const float* __restrict__ A,
                                                      float* __restrict__ invn) {
    __shared__ float red[256];
    const int mB = blockIdx.x * 16;            // 64 blocks
    const int mo = threadIdx.x & 15;
    const int dg = threadIdx.x >> 4;           // 16 d-groups of 32
    float ss = 0.0f;
#pragma unroll 4
    for (int i = 0; i < 32; ++i) {
        float v = A[(size_t)(dg * 32 + i) * M_DIM + mB + mo];
        ss = fmaf(v, v, ss);
    }
    red[threadIdx.x] = ss;
    __syncthreads();
    for (int s = 128; s >= 16; s >>= 1) {
        if (threadIdx.x < s) red[threadIdx.x] += red[threadIdx.x + s];
        __syncthreads();
    }
    if (threadIdx.x < 16)
        invn[mB + mo] = 1.0f / fmaxf(sqrtf(red[threadIdx.x]), 1e-12f);
}

// ---------- K2: z fp32 -> bf16 (same layout) ----------
__global__ __launch_bounds__(256) void zconv_kernel(const float* __restrict__ z,
                                                    ushort* __restrict__ zb) {
    const size_t i = ((size_t)blockIdx.x * 256 + threadIdx.x) * 8;   // 1024 blocks, exact
    const float4 a = *reinterpret_cast<const float4*>(&z[i]);
    const float4 b = *reinterpret_cast<const float4*>(&z[i + 4]);
    uint4 p;
    p.x = (unsigned)f2bf(a.x) | ((unsigned)f2bf(a.y) << 16);
    p.y = (unsigned)f2bf(a.z) | ((unsigned)f2bf(a.w) << 16);
    p.z = (unsigned)f2bf(b.x) | ((unsigned)f2bf(b.y) << 16);
    p.w = (unsigned)f2bf(b.z) | ((unsigned)f2bf(b.w) << 16);
    *reinterpret_cast<uint4*>(&zb[i]) = p;
}

// ---------- K3: Ant[m][d] = A[d][m] * invn[m], bf16 (LDS tile transpose) ----------
__global__ __launch_bounds__(256) void atrans_kernel(const float* __restrict__ A,
                                                     const float* __restrict__ invn,
                                                     ushort* __restrict__ ant) {
    __shared__ float tile[64][65];
    const int dB = blockIdx.x * 64;            // 8
    const int mB = blockIdx.y * 64;            // 16
#pragma unroll
    for (int it = 0; it < 4; ++it) {
        const int r = it * 16 + (threadIdx.x >> 4);
        const int c = (threadIdx.x & 15) * 4;
        const float4 v = *reinterpret_cast<const float4*>(&A[(size_t)(dB + r) * M_DIM + mB + c]);
        tile[r][c] = v.x; tile[r][c + 1] = v.y; tile[r][c + 2] = v.z; tile[r][c + 3] = v.w;
    }
    __syncthreads();
#pragma unroll
    for (int it = 0; it < 2; ++it) {
        const int ci = it * 256 + threadIdx.x;
        const int orow = ci >> 3;              // 0..63 (m-local)
        const int oc = (ci & 7) * 8;           // 0..56 (d-local)
        const float sc = invn[mB + orow];
        uint4 p;
        p.x = (unsigned)f2bf(tile[oc + 0][orow] * sc) | ((unsigned)f2bf(tile[oc + 1][orow] * sc) << 16);
        p.y = (unsigned)f2bf(tile[oc + 2][orow] * sc) | ((unsigned)f2bf(tile[oc + 3][orow] * sc) << 16);
        p.z = (unsigned)f2bf(tile[oc + 4][orow] * sc) | ((unsigned)f2bf(tile[oc + 5][orow] * sc) << 16);
        p.w = (unsigned)f2bf(tile[oc + 6][orow] * sc) | ((unsigned)f2bf(tile[oc + 7][orow] * sc) << 16);
        *reinterpret_cast<uint4*>(&ant[(size_t)(mB + orow) * D_DIM + dB + oc]) = p;
    }
}

// ---------- K4: fused bf16-MFMA GEMM + CF statistic ----------
// block: 256 thr (4 waves, 2x2), tile 128 rows (all b of one t) x 64 cols; K=512, BK=64.
__global__ __launch_bounds__(256) void fused_kernel(const ushort* __restrict__ zb,
                                                    const ushort* __restrict__ ant,
                                                    float* __restrict__ partials) {
    __shared__ __align__(16) ushort As[128][72];    // +16B pad per row
    __shared__ __align__(16) ushort Bs[64][72];
    __shared__ float wred[2][32][32];               // [wc][col][k | 16+k]
    __shared__ float bred[2];

    const int tid  = threadIdx.x;
    const int t    = blockIdx.x;                    // 0..31
    const int mB   = blockIdx.y * 64;               // 0..960
    const int wave = tid >> 6;
    const int lane = tid & 63;
    const int wr   = wave >> 1;                     // row half
    const int wc   = wave & 1;                      // col half
    const int l15  = lane & 15;
    const int lhi  = lane >> 4;

    const ushort* zrow = zb + (size_t)t * B_DIM * D_DIM;

    f32x4 acc[4][2];
#pragma unroll
    for (int fm = 0; fm < 4; ++fm)
#pragma unroll
        for (int fn = 0; fn < 2; ++fn) acc[fm][fn] = (f32x4)(0.0f);

    for (int k0 = 0; k0 < D_DIM; k0 += 64) {
        uint4 aReg[4], bReg[2];
#pragma unroll
        for (int q = 0; q < 4; ++q) {
            const int ci = tid + 256 * q, r = ci >> 3, c = ci & 7;
            aReg[q] = *reinterpret_cast<const uint4*>(&zrow[(size_t)r * D_DIM + k0 + c * 8]);
        }
#pragma unroll
        for (int q = 0; q < 2; ++q) {
            const int ci = tid + 256 * q, r = ci >> 3, c = ci & 7;
            bReg[q] = *reinterpret_cast<const uint4*>(&ant[(size_t)(mB + r) * D_DIM + k0 + c * 8]);
        }
        __syncthreads();                            // prior MFMA reads done
#pragma unroll
        for (int q = 0; q < 4; ++q) {
            const int ci = tid + 256 * q, r = ci >> 3, c = ci & 7;
            *reinterpret_cast<uint4*>(&As[r][c * 8]) = aReg[q];
        }
#pragma unroll
        for (int q = 0; q < 2; ++q) {
            const int ci = tid + 256 * q, r = ci >> 3, c = ci & 7;
            *reinterpret_cast<uint4*>(&Bs[r][c * 8]) = bReg[q];
        }
        __syncthreads();

#pragma unroll
        for (int ks = 0; ks < 2; ++ks) {
            bf16x8 af[4], bf[2];
#pragma unroll
            for (int fm = 0; fm < 4; ++fm)
                af[fm] = *reinterpret_cast<const bf16x8*>(&As[wr * 64 + fm * 16 + l15][ks * 32 + lhi * 8]);
#pragma unroll
            for (int fn = 0; fn < 2; ++fn)
                bf[fn] = *reinterpret_cast<const bf16x8*>(&Bs[wc * 32 + fn * 16 + l15][ks * 32 + lhi * 8]);
#pragma unroll
            for (int fm = 0; fm < 4; ++fm)
#pragma unroll
                for (int fn = 0; fn < 2; ++fn)
                    acc[fm][fn] = __builtin_amdgcn_mfma_f32_16x16x32_bf16(af[fm], bf[fn], acc[fm][fn], 0, 0, 0);
        }
    }

    // ---- per-lane CF accumulation (Chebyshev recurrence over 16 knots) ----
    float accC[2][16], accS[2][16];
#pragma unroll
    for (int fn = 0; fn < 2; ++fn)
#pragma unroll
        for (int k = 0; k < 16; ++k) { accC[fn][k] = 0.0f; accS[fn][k] = 0.0f; }

#pragma unroll
    for (int fn = 0; fn < 2; ++fn)
#pragma unroll
        for (int fm = 0; fm < 4; ++fm)
#pragma unroll
            for (int r = 0; r < 4; ++r) {
                const float theta = acc[fm][fn][r] * DT;
                float s1, c1;
                __sincosf(theta, &s1, &c1);
                const float c2 = 2.0f * c1;
                float cp = 1.0f, cc = c1, sp = 0.0f, sc = s1;
                accC[fn][0] += cc; accS[fn][0] += sc;
#pragma unroll
                for (int k = 1; k < 16; ++k) {
                    const float cn = fmaf(c2, cc, -cp);
                    const float sn = fmaf(c2, sc, -sp);
                    cp = cc; cc = cn; sp = sc; sc = sn;
                    accC[fn][k] += cc; accS[fn][k] += sc;
                }
            }

    // reduce over the wave's 64 rows (lane>>4 groups)
#pragma unroll
    for (int fn = 0; fn < 2; ++fn)
#pragma unroll
        for (int k = 0; k < 16; ++k) {
            accC[fn][k] += __shfl_xor(accC[fn][k], 16);
            accC[fn][k] += __shfl_xor(accC[fn][k], 32);
            accS[fn][k] += __shfl_xor(accS[fn][k], 16);
            accS[fn][k] += __shfl_xor(accS[fn][k], 32);
        }

    if (wr == 0 && lane < 16) {
#pragma unroll
        for (int fn = 0; fn < 2; ++fn)
#pragma unroll
            for (int k = 0; k < 16; ++k) {
                wred[wc][fn * 16 + l15][k]      = accC[fn][k];
                wred[wc][fn * 16 + l15][16 + k] = accS[fn][k];
            }
    }
    __syncthreads();

    if (wr == 1) {
        const float invB = 1.0f / 128.0f;
        float s = 0.0f;
#pragma unroll
        for (int fn = 0; fn < 2; ++fn) {
#pragma unroll
            for (int kk = 1; kk <= 16; ++kk) {
                const float tk = DT * (float)kk;
                const float g  = __expf(-0.5f * tk * tk);
                const float w  = ((kk == 16) ? DT : 2.0f * DT) * g;
                const float totC = wred[wc][fn * 16 + l15][kk - 1]      + accC[fn][kk - 1];
                const float totS = wred[wc][fn * 16 + l15][16 + kk - 1] + accS[fn][kk - 1];
                const float cm = fmaf(totC, invB, -g);
                const float sm = totS * invB;
                s = fmaf(w, fmaf(cm, cm, sm * sm), s);
            }
        }
        // butterfly over all 64 lanes: each col counted 4x
#pragma unroll
        for (int m = 1; m < 64; m <<= 1) s += __shfl_xor(s, m);
        if (lane == 0) bred[wc] = s;
    }
    __syncthreads();
    if (tid == 0)
        partials[blockIdx.y * 32 + blockIdx.x] = (bred[0] + bred[1]) * 0.25f * 128.0f;
}

// ---------- K5: final reduce of 512 partials ----------
__global__ __launch_bounds__(256) void finalize_kernel(const float* __restrict__ partials,
                                                       float* __restrict__ out) {
    __shared__ float red[256];
    const int tid = threadIdx.x;
    red[tid] = partials[tid] + partials[tid + 256];
    __syncthreads();
    for (int s = 128; s > 0; s >>= 1) {
        if (tid < s) red[tid] += red[tid + s];
        __syncthreads();
    }
    if (tid == 0) out[0] = red[0] * (1.0f / (float)(T_DIM * M_DIM));
}

extern "C" void kernel_launch(void* const* d_in, const int* in_sizes, int n_in,
                              void* d_out, int out_size, void* d_ws, size_t ws_size,
                              hipStream_t stream) {
    const float* z = (const float*)d_in[0];   // (32,128,512)
    const float* A = (const float*)d_in[1];   // (512,1024)
    float* out = (float*)d_out;

    float*  invn     = (float*)d_ws;                                    // 4 KB
    float*  partials = invn + 1024;                                     // 2 KB
    ushort* zb  = (ushort*)((char*)d_ws + 8192);                        // 4 MB
    ushort* ant = (ushort*)((char*)d_ws + 8192 + (size_t)T_DIM * B_DIM * D_DIM * 2); // 1 MB

    colnorm_kernel<<<64, 256, 0, stream>>>(A, invn);
    zconv_kernel<<<1024, 256, 0, stream>>>(z, zb);
    atrans_kernel<<<dim3(8, 16), 256, 0, stream>>>(A, invn, ant);

    fused_kernel<<<dim3(T_DIM, M_DIM / 64), 256, 0, stream>>>(zb, ant, partials);

    finalize_kernel<<<1, 256, 0, stream>>>(partials, out);
}